// Round 13
// baseline (742.301 us; speedup 1.0000x reference)
//
#include <hip/hip_runtime.h>

// Problem constants (match reference)
constexpr int kN = 100000;   // nodes
constexpr int kE = 400000;   // edges per relation
constexpr int kR = 4;        // relations
constexpr int kG = 64;       // graphs
constexpr int kIN = 64;      // input feature dim
constexpr int kH = 128;      // hidden dim
constexpr int kC = 2;        // classes
constexpr int kMAXD = 24;    // ELL width; P(in-deg>24) ~ 1e-11 per node

// ---------------- workspace layout (bytes) ----------------
constexpr size_t SZ_HB16 = (size_t)kN * kH * 2;    // 25,600,000 (bf16 h)
constexpr size_t SZ_RN   = (size_t)kR * kN * 4;    // 1,600,000
constexpr size_t OFF_HA   = 0;
constexpr size_t OFF_HB   = OFF_HA + SZ_HB16;
constexpr size_t OFF_DEGO = OFF_HB + SZ_HB16;      // int [R*N], zeroed
constexpr size_t OFF_CNT  = OFF_DEGO + SZ_RN;      // int [R*N], zeroed (ELL cursor = deg_i)
constexpr size_t OFF_ELL  = OFF_CNT + SZ_RN;       // int2 [R*N*kMAXD] = 76.8 MB
constexpr size_t OFF_POOL = OFF_ELL + (size_t)kR * kN * kMAXD * 8; // f32 [G*H], zeroed
constexpr size_t OFF_Z1   = OFF_POOL + (size_t)kG * kH * 4;
constexpr size_t OFF_Z2   = OFF_Z1 + (size_t)kG * kH * 4;
constexpr size_t OFF_WB1  = OFF_Z2 + (size_t)kG * kH * 4;       // bf16 [H][R*H]
constexpr size_t OFF_WB2  = OFF_WB1 + (size_t)kH * kR * kH * 2; // bf16 [H][R*H]

// ---------------- types / bf16 helpers (RNE) ----------------
typedef __attribute__((ext_vector_type(8))) short bf16x8;
typedef __attribute__((ext_vector_type(4))) float f32x4;

__device__ inline unsigned short f2bf(float f) {
    unsigned u = __builtin_bit_cast(unsigned, f);
    u += 0x7FFFu + ((u >> 16) & 1u);
    return (unsigned short)(u >> 16);
}
__device__ inline float bf2f_lo(unsigned p) {
    unsigned u = p << 16;
    return __builtin_bit_cast(float, u);
}
__device__ inline float bf2f_hi(unsigned p) {
    unsigned u = p & 0xFFFF0000u;
    return __builtin_bit_cast(float, u);
}

// ---------------- graph build (ELL) ----------------

// out-degree histogram only (1.6M atomics)
__global__ void k_deg(const int* __restrict__ src, int* __restrict__ deg_o) {
    int i = blockIdx.x * blockDim.x + threadIdx.x;
    if (i >= kR * kE) return;
    int r = i / kE;
    atomicAdd(&deg_o[r * kN + src[i]], 1);
}

// ELL fill: slot claim IS the in-degree histogram; coef = rsqrt(deg_o[src]) inline.
__global__ void k_fill(const int* __restrict__ src, const int* __restrict__ dst,
                       const int* __restrict__ deg_o, int* __restrict__ cnt,
                       int2* __restrict__ ell) {
    int i = blockIdx.x * blockDim.x + threadIdx.x;
    if (i >= kR * kE) return;
    int r = i / kE;
    int s = src[i], d = dst[i];
    int pos = atomicAdd(&cnt[r * kN + d], 1);
    if (pos < kMAXD) {
        float co = rsqrtf((float)max(deg_o[r * kN + s], 1));
        ell[(size_t)(r * kN + d) * kMAXD + pos] = make_int2(s, __builtin_bit_cast(int, co));
    }
}

// ---------------- W convert (both layers): f32 [R][H][H] -> bf16 [H][R*H] ----
__global__ void k_wconv(const float* __restrict__ W1, const float* __restrict__ W2,
                        unsigned short* __restrict__ Wbt1, unsigned short* __restrict__ Wbt2) {
    int i = blockIdx.x * 256 + threadIdx.x;      // over 2*R*H*H = 131072
    if (i >= 2 * kR * kH * kH) return;
    const float* W = (i < kR * kH * kH) ? W1 : W2;
    unsigned short* Wbt = (i < kR * kH * kH) ? Wbt1 : Wbt2;
    int ii = i & (kR * kH * kH - 1);
    int r = ii >> 14; int kk = (ii >> 7) & 127; int j = ii & 127;
    Wbt[(size_t)j * (kR * kH) + r * kH + kk] = f2bf(W[ii]);
}

// ---------------- input linear (f32 in, bf16 out) ----------------
__global__ __launch_bounds__(256) void k_inlin(const float* __restrict__ x,
                                               const float* __restrict__ W,
                                               const float* __restrict__ b,
                                               unsigned short* __restrict__ h) {
    __shared__ float Ws[64][128];
    __shared__ float xs[64][64];
    int t = threadIdx.x;
    int n0 = blockIdx.x * 64;
    for (int i = t; i < 64 * 128; i += 256) Ws[i >> 7][i & 127] = W[i];
    for (int i = t; i < 64 * 64; i += 256) {
        int rr = i >> 6, cc = i & 63;
        int n = n0 + rr;
        xs[rr][cc] = (n < kN) ? x[(size_t)n * kIN + cc] : 0.f;
    }
    __syncthreads();
    int jg = t & 31, j0 = jg * 4, rg = t >> 5; // rg in 0..7, 8 rows each
    float acc[8][4] = {};
    for (int k = 0; k < 64; k++) {
        float4 wv = *(const float4*)&Ws[k][j0];
        #pragma unroll
        for (int i = 0; i < 8; i++) {
            float av = xs[rg * 8 + i][k];
            acc[i][0] += av * wv.x; acc[i][1] += av * wv.y;
            acc[i][2] += av * wv.z; acc[i][3] += av * wv.w;
        }
    }
    #pragma unroll
    for (int i = 0; i < 8; i++) {
        int n = n0 + rg * 8 + i;
        if (n < kN) {
            ushort4 res;
            res.x = f2bf(fmaxf(acc[i][0] + b[j0 + 0], 0.f));
            res.y = f2bf(fmaxf(acc[i][1] + b[j0 + 1], 0.f));
            res.z = f2bf(fmaxf(acc[i][2] + b[j0 + 2], 0.f));
            res.w = f2bf(fmaxf(acc[i][3] + b[j0 + 3], 0.f));
            *(ushort4*)&h[(size_t)n * kH + j0] = res;
        }
    }
}

// ---------------- fused RGCN layer: ELL concat-gather + MFMA (16-node) ------
// out(16x128) = relu?( As(16x512) @ Wcat(512x128) + sum_r b_r )
// 16 KB LDS -> up to 8 blocks/CU (wave-capped), double the prior occupancy.
__global__ __launch_bounds__(256, 8) void k_layer(
    const unsigned short* __restrict__ hin, const int2* __restrict__ ell,
    const int* __restrict__ cnt, const unsigned short* __restrict__ Wbt,
    const float* __restrict__ brel, unsigned short* __restrict__ out, int doRelu) {
    __shared__ char Asb[16 * 1024];               // bf16 [16][512], swizzled
    int t = threadIdx.x, wave = t >> 6, lane = t & 63;
    int grp = lane >> 4, li = lane & 15;          // 4 node-groups x 16 lanes
    int n0 = blockIdx.x * 16;                     // kN % 16 == 0

    // ---- gather phase: each 16-lane group owns 1 node x 4 relations
    {
        int ni = wave * 4 + grp;                  // node row 0..15
        int n = n0 + ni;
        #pragma unroll
        for (int r = 0; r < kR; r++) {
            int c = min(cnt[r * kN + n], kMAXD);
            const int2* ep = ell + (size_t)(r * kN + n) * kMAXD;
            float rsi = rsqrtf((float)max(c, 1));
            int cm = c;
            cm = max(cm, __shfl_xor(cm, 16));
            cm = max(cm, __shfl_xor(cm, 32));
            float a0 = 0.f, a1 = 0.f, a2 = 0.f, a3 = 0.f;
            float a4 = 0.f, a5 = 0.f, a6 = 0.f, a7 = 0.f;
            for (int e0 = 0; e0 < cm; e0 += 8) {
                int2 ev[8];
                #pragma unroll
                for (int u = 0; u < 8; u++) ev[u] = ep[min(e0 + u, kMAXD - 1)];
                uint4 pv[8];
                float co[8];
                #pragma unroll
                for (int u = 0; u < 8; u++) {
                    bool k = (e0 + u) < c;
                    int idx = k ? ev[u].x : 0;
                    co[u] = k ? __builtin_bit_cast(float, ev[u].y) : 0.f;
                    pv[u] = *(const uint4*)(hin + (size_t)idx * kH + li * 8);
                }
                #pragma unroll
                for (int u = 0; u < 8; u++) {
                    float cu = co[u];
                    a0 += cu * bf2f_lo(pv[u].x); a1 += cu * bf2f_hi(pv[u].x);
                    a2 += cu * bf2f_lo(pv[u].y); a3 += cu * bf2f_hi(pv[u].y);
                    a4 += cu * bf2f_lo(pv[u].z); a5 += cu * bf2f_hi(pv[u].z);
                    a6 += cu * bf2f_lo(pv[u].w); a7 += cu * bf2f_hi(pv[u].w);
                }
            }
            a0 *= rsi; a1 *= rsi; a2 *= rsi; a3 *= rsi;
            a4 *= rsi; a5 *= rsi; a6 *= rsi; a7 *= rsi;
            uint4 pk;
            pk.x = (unsigned)f2bf(a0) | ((unsigned)f2bf(a1) << 16);
            pk.y = (unsigned)f2bf(a2) | ((unsigned)f2bf(a3) << 16);
            pk.z = (unsigned)f2bf(a4) | ((unsigned)f2bf(a5) << 16);
            pk.w = (unsigned)f2bf(a6) | ((unsigned)f2bf(a7) << 16);
            int byte = ni * 1024 + ((r * 256 + li * 16) ^ ((ni & 7) << 4));
            *(uint4*)(Asb + byte) = pk;
        }
    }
    __syncthreads();                              // the ONLY barrier

    // ---- MFMA phase: wave w covers cols w*32..w*32+31, rows 0..15
    int colA = lane & 15;                         // A row / B,C col within tile
    int kgrp = lane >> 4;                         // 0..3 (k sub-block)
    f32x4 acc0 = {}, acc1 = {};
    const unsigned short* Wb0 = Wbt + (size_t)(wave * 32 + colA) * 512;       // ct=0
    const unsigned short* Wb1 = Wbt + (size_t)(wave * 32 + 16 + colA) * 512;  // ct=1
    int rowA = colA;
    int abase = rowA * 1024;
    int asw = (rowA & 7) << 4;
    for (int kb = 0; kb < 16; kb++) {
        int kbyte = kb * 64 + kgrp * 16;          // byte offset of 8-k chunk
        bf16x8 af = *(const bf16x8*)(Asb + abase + (kbyte ^ asw));
        int koff = kb * 32 + kgrp * 8;
        bf16x8 bf0 = *(const bf16x8*)(Wb0 + koff);
        bf16x8 bf1 = *(const bf16x8*)(Wb1 + koff);
        acc0 = __builtin_amdgcn_mfma_f32_16x16x32_bf16(af, bf0, acc0, 0, 0, 0);
        acc1 = __builtin_amdgcn_mfma_f32_16x16x32_bf16(af, bf1, acc1, 0, 0, 0);
    }
    // ---- epilogue: bias (sum over relations) + relu + bf16 store
    int col0 = wave * 32 + colA;
    int col1 = wave * 32 + 16 + colA;
    float bias0 = brel[col0] + brel[128 + col0] + brel[256 + col0] + brel[384 + col0];
    float bias1 = brel[col1] + brel[128 + col1] + brel[256 + col1] + brel[384 + col1];
    #pragma unroll
    for (int j = 0; j < 4; j++) {
        int n = n0 + kgrp * 4 + j;
        float v0 = acc0[j] + bias0, v1 = acc1[j] + bias1;
        if (doRelu) { v0 = fmaxf(v0, 0.f); v1 = fmaxf(v1, 0.f); }
        out[(size_t)n * kH + col0] = f2bf(v0);
        out[(size_t)n * kH + col1] = f2bf(v1);
    }
}

// ---------------- pooling (stage A) + heads ----------------
__global__ void k_pool_acc(const unsigned short* __restrict__ h,
                           const int* __restrict__ gid,
                           float* __restrict__ pooled) {
    int j = threadIdx.x;                 // 128 threads = feature
    int base = blockIdx.x * 128;
    if (base >= kN) return;
    int end = min(base + 128, kN);
    int curg = gid[base];
    float acc = 0.f;
    for (int n = base; n < end; n++) {
        int g = gid[n];                  // uniform -> scalar load
        if (g != curg) {
            atomicAdd(&pooled[curg * kH + j], acc);
            acc = 0.f; curg = g;
        }
        unsigned short v = h[(size_t)n * kH + j];
        acc += __builtin_bit_cast(float, (unsigned)v << 16);
    }
    atomicAdd(&pooled[curg * kH + j], acc);
}

// MLP head layer; if gid!=null, first divides in[g,:] by graph-g node count
__global__ void k_head(const float* __restrict__ in, const float* __restrict__ W,
                       const float* __restrict__ b, float* __restrict__ outv,
                       int doRelu, const int* __restrict__ gid) {
    __shared__ float ps[128];
    int g = blockIdx.x, j = threadIdx.x;
    float v = in[g * kH + j];
    if (gid) {
        int lo = 0, hi = kN;
        while (lo < hi) { int m = (lo + hi) >> 1; if (gid[m] < g) lo = m + 1; else hi = m; }
        int s = lo;
        lo = s; hi = kN;
        while (lo < hi) { int m = (lo + hi) >> 1; if (gid[m] <= g) lo = m + 1; else hi = m; }
        v /= (float)max(lo - s, 1);
    }
    ps[j] = v;
    __syncthreads();
    float acc = b[j];
    for (int k = 0; k < kH; k++) acc += ps[k] * W[k * kH + j];
    outv[g * kH + j] = doRelu ? fmaxf(acc, 0.f) : acc;
}

__global__ void k_head3(const float* __restrict__ z, const float* __restrict__ W,
                        const float* __restrict__ b, float* __restrict__ outv) {
    int t = threadIdx.x; // 128 = 64 graphs * 2 classes
    int g = t >> 1, c = t & 1;
    float acc = b[c];
    for (int k = 0; k < kH; k++) acc += z[g * kH + k] * W[k * kC + c];
    outv[g * kC + c] = acc;
}

// ---------------- launch ----------------
extern "C" void kernel_launch(void* const* d_in, const int* in_sizes, int n_in,
                              void* d_out, int out_size, void* d_ws, size_t ws_size,
                              hipStream_t stream) {
    (void)in_sizes; (void)n_in; (void)out_size; (void)ws_size;
    const float* x    = (const float*)d_in[0];
    const int*   src  = (const int*)d_in[1];
    const int*   dst  = (const int*)d_in[2];
    const int*   gid  = (const int*)d_in[3];
    const float* W_in = (const float*)d_in[4];
    const float* b_in = (const float*)d_in[5];
    const float* W1   = (const float*)d_in[6];
    const float* b1   = (const float*)d_in[7];
    const float* W2   = (const float*)d_in[8];
    const float* b2   = (const float*)d_in[9];
    const float* Wm1  = (const float*)d_in[10];
    const float* bm1  = (const float*)d_in[11];
    const float* Wm2  = (const float*)d_in[12];
    const float* bm2  = (const float*)d_in[13];
    const float* Wm3  = (const float*)d_in[14];
    const float* bm3  = (const float*)d_in[15];
    float* out = (float*)d_out;

    char* ws = (char*)d_ws;
    unsigned short* h_a = (unsigned short*)(ws + OFF_HA);
    unsigned short* h_b = (unsigned short*)(ws + OFF_HB);
    int*   deg_o   = (int*)(ws + OFF_DEGO);
    int*   cnt     = (int*)(ws + OFF_CNT);
    int2*  ell     = (int2*)(ws + OFF_ELL);
    float* pooled  = (float*)(ws + OFF_POOL);
    float* z1      = (float*)(ws + OFF_Z1);
    float* z2      = (float*)(ws + OFF_Z2);
    unsigned short* wb1 = (unsigned short*)(ws + OFF_WB1);
    unsigned short* wb2 = (unsigned short*)(ws + OFF_WB2);

    // zero deg_o + cnt (contiguous) and the pool accumulator
    hipMemsetAsync(ws + OFF_DEGO, 0, 2 * SZ_RN, stream);
    hipMemsetAsync(ws + OFF_POOL, 0, (size_t)kG * kH * 4, stream);

    int egrid = (kR * kE + 255) / 256;
    k_deg<<<egrid, 256, 0, stream>>>(src, deg_o);
    k_fill<<<egrid, 256, 0, stream>>>(src, dst, deg_o, cnt, ell);

    // weight conversion (both layers, one launch)
    k_wconv<<<(2 * kR * kH * kH + 255) / 256, 256, 0, stream>>>(W1, W2, wb1, wb2);

    k_inlin<<<(kN + 63) / 64, 256, 0, stream>>>(x, W_in, b_in, h_a);

    // layer 1: h_b = relu(sum_r A_r h_a W1_r + sum_r b1_r)
    k_layer<<<kN / 16, 256, 0, stream>>>(h_a, ell, cnt, wb1, b1, h_b, 1);
    // layer 2: h_a = sum_r A_r h_b W2_r + sum_r b2_r
    k_layer<<<kN / 16, 256, 0, stream>>>(h_b, ell, cnt, wb2, b2, h_a, 0);

    k_pool_acc<<<(kN + 127) / 128, 128, 0, stream>>>(h_a, gid, pooled);
    k_head<<<kG, 128, 0, stream>>>(pooled, Wm1, bm1, z1, 1, gid);   // divide by count here
    k_head<<<kG, 128, 0, stream>>>(z1, Wm2, bm2, z2, 1, nullptr);
    k_head3<<<1, 128, 0, stream>>>(z2, Wm3, bm3, out);
}

// Round 14
// 675.343 us; speedup vs baseline: 1.0991x; 1.0991x over previous
//
#include <hip/hip_runtime.h>

// Problem constants (match reference)
constexpr int kN = 100000;   // nodes
constexpr int kE = 400000;   // edges per relation
constexpr int kR = 4;        // relations
constexpr int kG = 64;       // graphs
constexpr int kIN = 64;      // input feature dim
constexpr int kH = 128;      // hidden dim
constexpr int kC = 2;        // classes
constexpr int kMAXD = 24;    // ELL width; P(in-deg>24) ~ 1e-11 per node

// ---------------- workspace layout (bytes) ----------------
constexpr size_t SZ_HB16 = (size_t)kN * kH * 2;    // 25,600,000 (bf16 h)
constexpr size_t SZ_RN   = (size_t)kR * kN * 4;    // 1,600,000
constexpr size_t OFF_HA   = 0;
constexpr size_t OFF_HB   = OFF_HA + SZ_HB16;
constexpr size_t OFF_DEGO = OFF_HB + SZ_HB16;      // int [R*N], zeroed
constexpr size_t OFF_CNT  = OFF_DEGO + SZ_RN;      // int [R*N], zeroed (ELL cursor = deg_i)
constexpr size_t OFF_ELL  = OFF_CNT + SZ_RN;       // int [R*N*kMAXD] = 38.4 MB (src only)
constexpr size_t OFF_POOL = OFF_ELL + (size_t)kR * kN * kMAXD * 4; // f32 [G*H], zeroed
constexpr size_t OFF_Z1   = OFF_POOL + (size_t)kG * kH * 4;
constexpr size_t OFF_Z2   = OFF_Z1 + (size_t)kG * kH * 4;
constexpr size_t OFF_WB1  = OFF_Z2 + (size_t)kG * kH * 4;       // bf16 [H][R*H]
constexpr size_t OFF_WB2  = OFF_WB1 + (size_t)kH * kR * kH * 2; // bf16 [H][R*H]

// ---------------- types / bf16 helpers (RNE) ----------------
typedef __attribute__((ext_vector_type(8))) short bf16x8;
typedef __attribute__((ext_vector_type(4))) float f32x4;

__device__ inline unsigned short f2bf(float f) {
    unsigned u = __builtin_bit_cast(unsigned, f);
    u += 0x7FFFu + ((u >> 16) & 1u);
    return (unsigned short)(u >> 16);
}
__device__ inline float bf2f_lo(unsigned p) {
    unsigned u = p << 16;
    return __builtin_bit_cast(float, u);
}
__device__ inline float bf2f_hi(unsigned p) {
    unsigned u = p & 0xFFFF0000u;
    return __builtin_bit_cast(float, u);
}

// ---------------- graph build: ONE pass over edges ----------------
// deg_o histogram + ELL slot claim + src write. No inter-dependency because
// the degree coefficient is now computed at gather time from deg_o.
__global__ void k_build(const int* __restrict__ src, const int* __restrict__ dst,
                        int* __restrict__ deg_o, int* __restrict__ cnt,
                        int* __restrict__ ell) {
    int i = blockIdx.x * blockDim.x + threadIdx.x;
    if (i >= kR * kE) return;
    int r = i / kE;
    int s = src[i], d = dst[i];
    atomicAdd(&deg_o[r * kN + s], 1);
    int pos = atomicAdd(&cnt[r * kN + d], 1);
    if (pos < kMAXD) {
        ell[(size_t)(r * kN + d) * kMAXD + pos] = s;
    }
}

// ---------------- W convert (both layers): f32 [R][H][H] -> bf16 [H][R*H] ----
__global__ void k_wconv(const float* __restrict__ W1, const float* __restrict__ W2,
                        unsigned short* __restrict__ Wbt1, unsigned short* __restrict__ Wbt2) {
    int i = blockIdx.x * 256 + threadIdx.x;      // over 2*R*H*H = 131072
    if (i >= 2 * kR * kH * kH) return;
    const float* W = (i < kR * kH * kH) ? W1 : W2;
    unsigned short* Wbt = (i < kR * kH * kH) ? Wbt1 : Wbt2;
    int ii = i & (kR * kH * kH - 1);
    int r = ii >> 14; int kk = (ii >> 7) & 127; int j = ii & 127;
    Wbt[(size_t)j * (kR * kH) + r * kH + kk] = f2bf(W[ii]);
}

// ---------------- input linear (f32 in, bf16 out) ----------------
__global__ __launch_bounds__(256) void k_inlin(const float* __restrict__ x,
                                               const float* __restrict__ W,
                                               const float* __restrict__ b,
                                               unsigned short* __restrict__ h) {
    __shared__ float Ws[64][128];
    __shared__ float xs[64][64];
    int t = threadIdx.x;
    int n0 = blockIdx.x * 64;
    for (int i = t; i < 64 * 128; i += 256) Ws[i >> 7][i & 127] = W[i];
    for (int i = t; i < 64 * 64; i += 256) {
        int rr = i >> 6, cc = i & 63;
        int n = n0 + rr;
        xs[rr][cc] = (n < kN) ? x[(size_t)n * kIN + cc] : 0.f;
    }
    __syncthreads();
    int jg = t & 31, j0 = jg * 4, rg = t >> 5; // rg in 0..7, 8 rows each
    float acc[8][4] = {};
    for (int k = 0; k < 64; k++) {
        float4 wv = *(const float4*)&Ws[k][j0];
        #pragma unroll
        for (int i = 0; i < 8; i++) {
            float av = xs[rg * 8 + i][k];
            acc[i][0] += av * wv.x; acc[i][1] += av * wv.y;
            acc[i][2] += av * wv.z; acc[i][3] += av * wv.w;
        }
    }
    #pragma unroll
    for (int i = 0; i < 8; i++) {
        int n = n0 + rg * 8 + i;
        if (n < kN) {
            ushort4 res;
            res.x = f2bf(fmaxf(acc[i][0] + b[j0 + 0], 0.f));
            res.y = f2bf(fmaxf(acc[i][1] + b[j0 + 1], 0.f));
            res.z = f2bf(fmaxf(acc[i][2] + b[j0 + 2], 0.f));
            res.w = f2bf(fmaxf(acc[i][3] + b[j0 + 3], 0.f));
            *(ushort4*)&h[(size_t)n * kH + j0] = res;
        }
    }
}

// ---------------- fused RGCN layer: ELL concat-gather + MFMA (32-node) ------
// out(32x128) = relu?( As(32x512) @ Wcat(512x128) + sum_r b_r )
// REVERTED to the proven 32-node block (R12: 120 us); coefficient rsqrt(deg_o)
// computed inline from the L2-resident degree array (ELL stores src only).
__global__ __launch_bounds__(256, 5) void k_layer(
    const unsigned short* __restrict__ hin, const int* __restrict__ ell,
    const int* __restrict__ cnt, const int* __restrict__ dego,
    const unsigned short* __restrict__ Wbt, const float* __restrict__ brel,
    unsigned short* __restrict__ out, int doRelu) {
    __shared__ char Asb[32 * 512 * 2];            // bf16 [32][512], swizzled
    int t = threadIdx.x, wave = t >> 6, lane = t & 63;
    int grp = lane >> 4, li = lane & 15;          // 4 node-groups x 16 lanes
    int n0 = blockIdx.x * 32;                     // kN % 32 == 0

    // ---- gather phase: 2 batches x 4 relations per 16-lane group
    #pragma unroll 1
    for (int batch = 0; batch < 2; batch++) {
        int ni = wave * 8 + batch * 4 + grp;      // node row 0..31
        int n = n0 + ni;
        #pragma unroll
        for (int r = 0; r < kR; r++) {
            int c = min(cnt[r * kN + n], kMAXD);
            const int* ep = ell + (size_t)(r * kN + n) * kMAXD;
            const int* dgo = dego + r * kN;
            float rsi = rsqrtf((float)max(c, 1));
            int cm = c;
            cm = max(cm, __shfl_xor(cm, 16));
            cm = max(cm, __shfl_xor(cm, 32));
            float a0 = 0.f, a1 = 0.f, a2 = 0.f, a3 = 0.f;
            float a4 = 0.f, a5 = 0.f, a6 = 0.f, a7 = 0.f;
            for (int e0 = 0; e0 < cm; e0 += 8) {
                int ev[8];
                #pragma unroll
                for (int u = 0; u < 8; u++) ev[u] = ep[min(e0 + u, kMAXD - 1)];
                uint4 pv[8];
                float co[8];
                #pragma unroll
                for (int u = 0; u < 8; u++) {
                    bool k = (e0 + u) < c;
                    int idx = k ? ev[u] : 0;
                    co[u] = k ? rsqrtf((float)max(dgo[idx], 1)) : 0.f;
                    pv[u] = *(const uint4*)(hin + (size_t)idx * kH + li * 8);
                }
                #pragma unroll
                for (int u = 0; u < 8; u++) {
                    float cu = co[u];
                    a0 += cu * bf2f_lo(pv[u].x); a1 += cu * bf2f_hi(pv[u].x);
                    a2 += cu * bf2f_lo(pv[u].y); a3 += cu * bf2f_hi(pv[u].y);
                    a4 += cu * bf2f_lo(pv[u].z); a5 += cu * bf2f_hi(pv[u].z);
                    a6 += cu * bf2f_lo(pv[u].w); a7 += cu * bf2f_hi(pv[u].w);
                }
            }
            a0 *= rsi; a1 *= rsi; a2 *= rsi; a3 *= rsi;
            a4 *= rsi; a5 *= rsi; a6 *= rsi; a7 *= rsi;
            uint4 pk;
            pk.x = (unsigned)f2bf(a0) | ((unsigned)f2bf(a1) << 16);
            pk.y = (unsigned)f2bf(a2) | ((unsigned)f2bf(a3) << 16);
            pk.z = (unsigned)f2bf(a4) | ((unsigned)f2bf(a5) << 16);
            pk.w = (unsigned)f2bf(a6) | ((unsigned)f2bf(a7) << 16);
            int byte = ni * 1024 + ((r * 256 + li * 16) ^ ((ni & 7) << 4));
            *(uint4*)(Asb + byte) = pk;
        }
    }
    __syncthreads();                              // the ONLY barrier

    // ---- MFMA phase: wave w covers cols w*32..w*32+31, rows 0..31
    int colA = lane & 15;                         // A row / B,C col within tile
    int kgrp = lane >> 4;                         // 0..3 (k sub-block)
    f32x4 acc00 = {}, acc01 = {}, acc10 = {}, acc11 = {};
    const unsigned short* Wb0 = Wbt + (size_t)(wave * 32 + colA) * 512;       // ct=0
    const unsigned short* Wb1 = Wbt + (size_t)(wave * 32 + 16 + colA) * 512;  // ct=1
    int rowA0 = colA, rowA1 = 16 + colA;
    int abase0 = rowA0 * 1024, abase1 = rowA1 * 1024;
    int asw0 = (rowA0 & 7) << 4, asw1 = (rowA1 & 7) << 4;
    for (int kb = 0; kb < 16; kb++) {
        int kbyte = kb * 64 + kgrp * 16;          // byte offset of 8-k chunk
        bf16x8 af0 = *(const bf16x8*)(Asb + abase0 + (kbyte ^ asw0));
        bf16x8 af1 = *(const bf16x8*)(Asb + abase1 + (kbyte ^ asw1));
        int koff = kb * 32 + kgrp * 8;
        bf16x8 bf0 = *(const bf16x8*)(Wb0 + koff);
        bf16x8 bf1 = *(const bf16x8*)(Wb1 + koff);
        acc00 = __builtin_amdgcn_mfma_f32_16x16x32_bf16(af0, bf0, acc00, 0, 0, 0);
        acc01 = __builtin_amdgcn_mfma_f32_16x16x32_bf16(af0, bf1, acc01, 0, 0, 0);
        acc10 = __builtin_amdgcn_mfma_f32_16x16x32_bf16(af1, bf0, acc10, 0, 0, 0);
        acc11 = __builtin_amdgcn_mfma_f32_16x16x32_bf16(af1, bf1, acc11, 0, 0, 0);
    }
    // ---- epilogue: bias (sum over relations) + relu + bf16 store
    int col0 = wave * 32 + colA;
    int col1 = wave * 32 + 16 + colA;
    float bias0 = brel[col0] + brel[128 + col0] + brel[256 + col0] + brel[384 + col0];
    float bias1 = brel[col1] + brel[128 + col1] + brel[256 + col1] + brel[384 + col1];
    #pragma unroll
    for (int j = 0; j < 4; j++) {
        int nA = n0 + kgrp * 4 + j;           // ri=0 rows
        int nB = n0 + 16 + kgrp * 4 + j;      // ri=1 rows
        float v00 = acc00[j] + bias0, v01 = acc01[j] + bias1;
        float v10 = acc10[j] + bias0, v11 = acc11[j] + bias1;
        if (doRelu) {
            v00 = fmaxf(v00, 0.f); v01 = fmaxf(v01, 0.f);
            v10 = fmaxf(v10, 0.f); v11 = fmaxf(v11, 0.f);
        }
        out[(size_t)nA * kH + col0] = f2bf(v00);
        out[(size_t)nA * kH + col1] = f2bf(v01);
        out[(size_t)nB * kH + col0] = f2bf(v10);
        out[(size_t)nB * kH + col1] = f2bf(v11);
    }
}

// ---------------- pooling (stage A) + heads ----------------
__global__ void k_pool_acc(const unsigned short* __restrict__ h,
                           const int* __restrict__ gid,
                           float* __restrict__ pooled) {
    int j = threadIdx.x;                 // 128 threads = feature
    int base = blockIdx.x * 128;
    if (base >= kN) return;
    int end = min(base + 128, kN);
    int curg = gid[base];
    float acc = 0.f;
    for (int n = base; n < end; n++) {
        int g = gid[n];                  // uniform -> scalar load
        if (g != curg) {
            atomicAdd(&pooled[curg * kH + j], acc);
            acc = 0.f; curg = g;
        }
        unsigned short v = h[(size_t)n * kH + j];
        acc += __builtin_bit_cast(float, (unsigned)v << 16);
    }
    atomicAdd(&pooled[curg * kH + j], acc);
}

// MLP head layer; if gid!=null, first divides in[g,:] by graph-g node count
__global__ void k_head(const float* __restrict__ in, const float* __restrict__ W,
                       const float* __restrict__ b, float* __restrict__ outv,
                       int doRelu, const int* __restrict__ gid) {
    __shared__ float ps[128];
    int g = blockIdx.x, j = threadIdx.x;
    float v = in[g * kH + j];
    if (gid) {
        int lo = 0, hi = kN;
        while (lo < hi) { int m = (lo + hi) >> 1; if (gid[m] < g) lo = m + 1; else hi = m; }
        int s = lo;
        lo = s; hi = kN;
        while (lo < hi) { int m = (lo + hi) >> 1; if (gid[m] <= g) lo = m + 1; else hi = m; }
        v /= (float)max(lo - s, 1);
    }
    ps[j] = v;
    __syncthreads();
    float acc = b[j];
    for (int k = 0; k < kH; k++) acc += ps[k] * W[k * kH + j];
    outv[g * kH + j] = doRelu ? fmaxf(acc, 0.f) : acc;
}

__global__ void k_head3(const float* __restrict__ z, const float* __restrict__ W,
                        const float* __restrict__ b, float* __restrict__ outv) {
    int t = threadIdx.x; // 128 = 64 graphs * 2 classes
    int g = t >> 1, c = t & 1;
    float acc = b[c];
    for (int k = 0; k < kH; k++) acc += z[g * kH + k] * W[k * kC + c];
    outv[g * kC + c] = acc;
}

// ---------------- launch ----------------
extern "C" void kernel_launch(void* const* d_in, const int* in_sizes, int n_in,
                              void* d_out, int out_size, void* d_ws, size_t ws_size,
                              hipStream_t stream) {
    (void)in_sizes; (void)n_in; (void)out_size; (void)ws_size;
    const float* x    = (const float*)d_in[0];
    const int*   src  = (const int*)d_in[1];
    const int*   dst  = (const int*)d_in[2];
    const int*   gid  = (const int*)d_in[3];
    const float* W_in = (const float*)d_in[4];
    const float* b_in = (const float*)d_in[5];
    const float* W1   = (const float*)d_in[6];
    const float* b1   = (const float*)d_in[7];
    const float* W2   = (const float*)d_in[8];
    const float* b2   = (const float*)d_in[9];
    const float* Wm1  = (const float*)d_in[10];
    const float* bm1  = (const float*)d_in[11];
    const float* Wm2  = (const float*)d_in[12];
    const float* bm2  = (const float*)d_in[13];
    const float* Wm3  = (const float*)d_in[14];
    const float* bm3  = (const float*)d_in[15];
    float* out = (float*)d_out;

    char* ws = (char*)d_ws;
    unsigned short* h_a = (unsigned short*)(ws + OFF_HA);
    unsigned short* h_b = (unsigned short*)(ws + OFF_HB);
    int*   deg_o   = (int*)(ws + OFF_DEGO);
    int*   cnt     = (int*)(ws + OFF_CNT);
    int*   ell     = (int*)(ws + OFF_ELL);
    float* pooled  = (float*)(ws + OFF_POOL);
    float* z1      = (float*)(ws + OFF_Z1);
    float* z2      = (float*)(ws + OFF_Z2);
    unsigned short* wb1 = (unsigned short*)(ws + OFF_WB1);
    unsigned short* wb2 = (unsigned short*)(ws + OFF_WB2);

    // zero deg_o + cnt (contiguous) and the pool accumulator
    hipMemsetAsync(ws + OFF_DEGO, 0, 2 * SZ_RN, stream);
    hipMemsetAsync(ws + OFF_POOL, 0, (size_t)kG * kH * 4, stream);

    int egrid = (kR * kE + 255) / 256;
    k_build<<<egrid, 256, 0, stream>>>(src, dst, deg_o, cnt, ell);

    // weight conversion (both layers, one launch)
    k_wconv<<<(2 * kR * kH * kH + 255) / 256, 256, 0, stream>>>(W1, W2, wb1, wb2);

    k_inlin<<<(kN + 63) / 64, 256, 0, stream>>>(x, W_in, b_in, h_a);

    // layer 1: h_b = relu(sum_r A_r h_a W1_r + sum_r b1_r)
    k_layer<<<kN / 32, 256, 0, stream>>>(h_a, ell, cnt, deg_o, wb1, b1, h_b, 1);
    // layer 2: h_a = sum_r A_r h_b W2_r + sum_r b2_r
    k_layer<<<kN / 32, 256, 0, stream>>>(h_b, ell, cnt, deg_o, wb2, b2, h_a, 0);

    k_pool_acc<<<(kN + 127) / 128, 128, 0, stream>>>(h_a, gid, pooled);
    k_head<<<kG, 128, 0, stream>>>(pooled, Wm1, bm1, z1, 1, gid);   // divide by count here
    k_head<<<kG, 128, 0, stream>>>(z1, Wm2, bm2, z2, 1, nullptr);
    k_head3<<<1, 128, 0, stream>>>(z2, Wm3, bm3, out);
}